// Round 1
// baseline (425.264 us; speedup 1.0000x reference)
//
#include <hip/hip_runtime.h>
#include <hip/hip_bf16.h>
#include <math.h>

typedef __bf16 bf16;
typedef __bf16 bf16x8 __attribute__((ext_vector_type(8)));
typedef float f32x4 __attribute__((ext_vector_type(4)));

#define MFMA16(a, b, c) __builtin_amdgcn_mfma_f32_16x16x32_bf16((a), (b), (c), 0, 0, 0)

static constexpr int Bsz = 2, Tsz = 2048, Csz = 2048, Hn = 16, Dh = 128;
static constexpr float ATTN_SCALE = 0.08838834764831845f; // 1/sqrt(128)

__device__ __forceinline__ void gld16(const void* src, void* dst) {
    __builtin_amdgcn_global_load_lds((__attribute__((address_space(1))) void*)src,
                                     (__attribute__((address_space(3))) void*)dst,
                                     16, 0, 0);
}

// ---------------- cast x (f32 -> bf16), 8 elems/thread ----------------
__global__ __launch_bounds__(256) void cast_x_kernel(const float* __restrict__ x,
                                                     bf16* __restrict__ o, int n8) {
    int i = blockIdx.x * 256 + threadIdx.x;
    if (i >= n8) return;
    const float4* x4 = (const float4*)x;
    float4 a = x4[2 * i], b = x4[2 * i + 1];
    bf16x8 v;
    v[0] = (bf16)a.x; v[1] = (bf16)a.y; v[2] = (bf16)a.z; v[3] = (bf16)a.w;
    v[4] = (bf16)b.x; v[5] = (bf16)b.y; v[6] = (bf16)b.z; v[7] = (bf16)b.w;
    ((bf16x8*)o)[i] = v;
}

// ---------------- tiled transpose-cast: out[c][r] = in[r][c] ----------------
template <typename TIN>
__global__ __launch_bounds__(256) void transpose_cast_kernel(const TIN* __restrict__ in,
                                                             bf16* __restrict__ out,
                                                             int R, int Cc) {
    __shared__ float tile[64][65];
    const int tx = threadIdx.x, ty = threadIdx.y;
    in  += (size_t)blockIdx.z * R * Cc;
    out += (size_t)blockIdx.z * R * Cc;
    const int c0 = blockIdx.x * 64, r0 = blockIdx.y * 64;
#pragma unroll
    for (int j = 0; j < 16; ++j) {
        int rr = ty + j * 4;
        tile[rr][tx] = (float)in[(size_t)(r0 + rr) * Cc + c0 + tx];
    }
    __syncthreads();
#pragma unroll
    for (int j = 0; j < 16; ++j) {
        int cc = ty + j * 4;
        out[(size_t)(c0 + cc) * R + r0 + tx] = (bf16)tile[tx][cc];
    }
}

// ---------------- rope cos/sin table: cs[t*64+i] = (cos, sin)(t * theta_i) ----------------
__global__ __launch_bounds__(256) void cossin_kernel(float2* __restrict__ cs) {
    int idx = blockIdx.x * 256 + threadIdx.x; // 2048*64
    int t = idx >> 6, i = idx & 63;
    float theta = 1.0f / powf(10000.0f, (float)(2 * i) / 128.0f);
    float ang = (float)t * theta;
    cs[idx] = make_float2(cosf(ang), sinf(ang));
}

// ---------------- 128x128 bf16 GEMM, B^T input (gemm_bt), BK=64 ----------------
// MODE 0: Cf[m][n] = acc (f32). MODE 1: fused rope + qkv head split.
template <int MODE>
__global__ __launch_bounds__(256)
void gemm128_bt(const bf16* __restrict__ A, const bf16* __restrict__ Bt,
                float* __restrict__ Cf,
                bf16* __restrict__ Oq, bf16* __restrict__ Ok, bf16* __restrict__ Ov,
                const float2* __restrict__ cs,
                int M, int N, int K) {
    __shared__ bf16 sA[128 * 64];
    __shared__ bf16 sB[128 * 64];
    const int tid = threadIdx.x;
    const int lane = tid & 63, wv = tid >> 6;
    const int wr = wv >> 1, wc = wv & 1;
    const int lo16 = lane & 15, hi4 = lane >> 4;
    const int row0 = blockIdx.y << 7, col0 = blockIdx.x << 7;

    f32x4 acc[4][4] = {};

    const int nkt = K >> 6;
    for (int kt = 0; kt < nkt; ++kt) {
        const int kbase = kt << 6;
#pragma unroll
        for (int c = 0; c < 4; ++c) {
            const int o16 = (c << 8) + tid;
            const int row = o16 >> 3, u = o16 & 7;
            const int colel = kbase + ((u ^ (row & 7)) << 3); // pre-swizzled source
            gld16(A  + (size_t)(row0 + row) * K + colel,
                  (char*)sA + (((c << 8) + (wv << 6)) << 4));
            gld16(Bt + (size_t)(col0 + row) * K + colel,
                  (char*)sB + (((c << 8) + (wv << 6)) << 4));
        }
        __syncthreads();
#pragma unroll
        for (int ks = 0; ks < 2; ++ks) {
            bf16x8 af[4], bfv[4];
#pragma unroll
            for (int mi = 0; mi < 4; ++mi) {
                const int ar = (wr << 6) + (mi << 4) + lo16;
                af[mi] = *(const bf16x8*)((const char*)sA + ar * 128 +
                          (((ks << 6) + (hi4 << 4)) ^ ((ar & 7) << 4)));
            }
#pragma unroll
            for (int ni = 0; ni < 4; ++ni) {
                const int bc = (wc << 4) + (ni << 5) + lo16;
                bfv[ni] = *(const bf16x8*)((const char*)sB + bc * 128 +
                           (((ks << 6) + (hi4 << 4)) ^ ((bc & 7) << 4)));
            }
#pragma unroll
            for (int mi = 0; mi < 4; ++mi)
#pragma unroll
                for (int ni = 0; ni < 4; ++ni)
                    acc[mi][ni] = MFMA16(af[mi], bfv[ni], acc[mi][ni]);
        }
        __syncthreads();
    }

    if (MODE == 0) {
#pragma unroll
        for (int mi = 0; mi < 4; ++mi)
#pragma unroll
            for (int r = 0; r < 4; ++r) {
                const int gm = row0 + (wr << 6) + (mi << 4) + (hi4 << 2) + r;
                float* crow = Cf + (size_t)gm * N + col0 + (wc << 4) + lo16;
#pragma unroll
                for (int ni = 0; ni < 4; ++ni)
                    crow[ni << 5] = acc[mi][ni][r];
            }
    } else {
        const int seg = col0 >> 11;         // 0=q 1=k 2=v
        const int h = (col0 >> 7) & 15;
        if (seg < 2) {
            bf16* dst0 = (seg == 0) ? Oq : Ok;
#pragma unroll
            for (int mi = 0; mi < 4; ++mi)
#pragma unroll
                for (int r = 0; r < 4; ++r) {
                    const int gm = row0 + (wr << 6) + (mi << 4) + (hi4 << 2) + r;
                    const int b = gm >> 11, t = gm & 2047;
                    bf16* drow = dst0 + ((((size_t)b * Hn + h) * Tsz + t) << 7);
#pragma unroll
                    for (int ni = 0; ni < 2; ++ni) {
                        const int dlo = (wc << 4) + (ni << 5) + lo16; // in [0,64)
                        const float2 csv = cs[t * 64 + dlo];
                        const float vlo = acc[mi][ni][r];
                        const float vhi = acc[mi][ni + 2][r];
                        drow[dlo]      = (bf16)(vlo * csv.x - vhi * csv.y);
                        drow[dlo + 64] = (bf16)(vhi * csv.x + vlo * csv.y);
                    }
                }
        } else {
#pragma unroll
            for (int mi = 0; mi < 4; ++mi)
#pragma unroll
                for (int r = 0; r < 4; ++r) {
                    const int gm = row0 + (wr << 6) + (mi << 4) + (hi4 << 2) + r;
                    const int b = gm >> 11, t = gm & 2047;
                    bf16* drow = Ov + ((((size_t)b * Hn + h) * Tsz + t) << 7);
#pragma unroll
                    for (int ni = 0; ni < 4; ++ni)
                        drow[(wc << 4) + (ni << 5) + lo16] = (bf16)acc[mi][ni][r];
                }
        }
    }
}

// ---------------- causal flash attention: QBLK=64 (4 waves x 16 rows), KVBLK=32 ----------------
__global__ __launch_bounds__(256)
void attn_kernel(const bf16* __restrict__ Q, const bf16* __restrict__ K,
                 const bf16* __restrict__ Vt, bf16* __restrict__ Y) {
    __shared__ bf16 sK[32 * 128];   // [key][d], XOR-swizzled 16B units
    __shared__ bf16 sV[128 * 32];   // [d][key], XOR-swizzled
    __shared__ bf16 sP[4][16 * 40]; // per-wave P tile, padded rows (80B)
    const int tid = threadIdx.x, lane = tid & 63, wv = tid >> 6;
    const int lo16 = lane & 15, hi4 = lane >> 4;
    const int q0 = blockIdx.x << 6;
    const size_t bh = blockIdx.y;
    const int b = blockIdx.y >> 4, h = blockIdx.y & 15;
    const bf16* Kb = K + bh * (size_t)(Tsz * Dh);
    const bf16* Vb = Vt + bh * (size_t)(Tsz * Dh);

    const int qrow_base = q0 + (wv << 4);
    const bf16* Qb = Q + bh * (size_t)(Tsz * Dh) + (size_t)(qrow_base + lo16) * Dh;
    bf16x8 qf[4];
#pragma unroll
    for (int kc = 0; kc < 4; ++kc)
        qf[kc] = *(const bf16x8*)(Qb + (kc << 5) + (hi4 << 3));

    float m[4], lsum[4];
#pragma unroll
    for (int r = 0; r < 4; ++r) { m[r] = -1e30f; lsum[r] = 0.f; }
    f32x4 o[8] = {};

    const int ntiles = (q0 >> 5) + 2;
    for (int kt = 0; kt < ntiles; ++kt) {
        const int k0 = kt << 5;
#pragma unroll
        for (int c = 0; c < 2; ++c) {
            const int o16 = (c << 8) + tid;
            const int row = o16 >> 4, u = o16 & 15;
            gld16(Kb + (size_t)(k0 + row) * Dh + ((u ^ (row & 7)) << 3),
                  (char*)sK + (((c << 8) + (wv << 6)) << 4));
            const int rowv = o16 >> 2, uv = o16 & 3;
            gld16(Vb + (size_t)rowv * Tsz + k0 + ((uv ^ ((rowv >> 2) & 3)) << 3),
                  (char*)sV + (((c << 8) + (wv << 6)) << 4));
        }
        __syncthreads();
        if (k0 <= qrow_base + 15) {
            f32x4 s[2] = {};
#pragma unroll
            for (int cf = 0; cf < 2; ++cf) {
                const int key = lo16 + (cf << 4);
#pragma unroll
                for (int kc = 0; kc < 4; ++kc) {
                    bf16x8 kf = *(const bf16x8*)((const char*)sK + key * 256 +
                                (((kc << 6) + (hi4 << 4)) ^ ((key & 7) << 4)));
                    s[cf] = MFMA16(qf[kc], kf, s[cf]);
                }
            }
            const bool needmask = (k0 + 31 > qrow_base);
            float p[2][4], pm[4];
#pragma unroll
            for (int r = 0; r < 4; ++r) {
                const int qg = qrow_base + (hi4 << 2) + r;
#pragma unroll
                for (int cf = 0; cf < 2; ++cf) {
                    float v = s[cf][r] * ATTN_SCALE;
                    if (needmask && (k0 + lo16 + (cf << 4) > qg)) v = -1e30f;
                    p[cf][r] = v;
                }
                pm[r] = fmaxf(p[0][r], p[1][r]);
            }
#pragma unroll
            for (int off = 1; off < 16; off <<= 1)
#pragma unroll
                for (int r = 0; r < 4; ++r)
                    pm[r] = fmaxf(pm[r], __shfl_xor(pm[r], off));
            float sc[4], rs[4];
#pragma unroll
            for (int r = 0; r < 4; ++r) {
                const float mn = fmaxf(m[r], pm[r]);
                sc[r] = __expf(m[r] - mn);
                m[r] = mn;
                p[0][r] = __expf(p[0][r] - mn);
                p[1][r] = __expf(p[1][r] - mn);
                rs[r] = p[0][r] + p[1][r];
            }
#pragma unroll
            for (int off = 1; off < 16; off <<= 1)
#pragma unroll
                for (int r = 0; r < 4; ++r)
                    rs[r] += __shfl_xor(rs[r], off);
#pragma unroll
            for (int r = 0; r < 4; ++r) lsum[r] = lsum[r] * sc[r] + rs[r];
#pragma unroll
            for (int nf = 0; nf < 8; ++nf)
#pragma unroll
                for (int r = 0; r < 4; ++r) o[nf][r] *= sc[r];
            // P: C-layout regs -> per-wave LDS -> A-layout frag
            bf16* pw = sP[wv];
#pragma unroll
            for (int r = 0; r < 4; ++r) {
                const int prow = (hi4 << 2) + r;
                pw[prow * 40 + lo16]      = (bf16)p[0][r];
                pw[prow * 40 + lo16 + 16] = (bf16)p[1][r];
            }
            asm volatile("s_waitcnt lgkmcnt(0)" ::: "memory");
            __builtin_amdgcn_sched_barrier(0);
            const bf16x8 pf = *(const bf16x8*)(pw + lo16 * 40 + (hi4 << 3));
#pragma unroll
            for (int nf = 0; nf < 8; ++nf) {
                const int dd = lo16 + (nf << 4);
                bf16x8 vf = *(const bf16x8*)((const char*)sV + dd * 64 +
                            ((hi4 << 4) ^ (((dd >> 2) & 3) << 4)));
                o[nf] = MFMA16(pf, vf, o[nf]);
            }
        }
        __syncthreads();
    }
    const int t_base = qrow_base + (hi4 << 2);
#pragma unroll
    for (int r = 0; r < 4; ++r) {
        const float inv = 1.0f / lsum[r];
        const size_t rowoff = ((size_t)b * Tsz + (t_base + r)) * Csz + h * 128;
#pragma unroll
        for (int nf = 0; nf < 8; ++nf)
            Y[rowoff + lo16 + (nf << 4)] = (bf16)(o[nf][r] * inv);
    }
}

extern "C" void kernel_launch(void* const* d_in, const int* in_sizes, int n_in,
                              void* d_out, int out_size, void* d_ws, size_t ws_size,
                              hipStream_t stream) {
    const float* x      = (const float*)d_in[0];
    const float* w_attn = (const float*)d_in[1];
    const float* w_proj = (const float*)d_in[2];
    float* out = (float*)d_out;

    char* ws = (char*)d_ws;
    bf16* Xb  = (bf16*)(ws);                 // 4096x2048           16 MB
    bf16* Wat = (bf16*)(ws + 16777216);      // 6144x2048 (W^T)     24 MB
    bf16* Wpt = (bf16*)(ws + 41943040);      // 2048x2048 (W^T)      8 MB
    bf16* Qr  = (bf16*)(ws + 50331648);      // [B,H,T,D]           16 MB
    bf16* Kr  = (bf16*)(ws + 67108864);      // [B,H,T,D]           16 MB
    bf16* Vb  = (bf16*)(ws + 83886080);      // [B,H,T,D]           16 MB
    bf16* Vt  = (bf16*)(ws + 100663296);     // [B,H,D,T]           16 MB
    bf16* Yb  = (bf16*)(ws + 117440512);     // [B,T,C]             16 MB
    float2* cs = (float2*)(ws + 134217728);  // [T,64]               1 MB

    // 1. casts / transposes / rope table
    cast_x_kernel<<<4096, 256, 0, stream>>>(x, Xb, (Bsz * Tsz * Csz) / 8);
    transpose_cast_kernel<float><<<dim3(96, 32, 1), dim3(64, 4), 0, stream>>>(w_attn, Wat, 2048, 6144);
    transpose_cast_kernel<float><<<dim3(32, 32, 1), dim3(64, 4), 0, stream>>>(w_proj, Wpt, 2048, 2048);
    cossin_kernel<<<512, 256, 0, stream>>>(cs);

    // 2. qkv GEMM with fused rope + head-split epilogue
    gemm128_bt<1><<<dim3(48, 32), 256, 0, stream>>>(Xb, Wat, nullptr, Qr, Kr, Vb, cs,
                                                    4096, 6144, 2048);
    // 3. V -> V^T per (b,h)
    transpose_cast_kernel<bf16><<<dim3(2, 32, 32), dim3(64, 4), 0, stream>>>(Vb, Vt, 2048, 128);

    // 4. causal flash attention
    attn_kernel<<<dim3(32, 32), 256, 0, stream>>>(Qr, Kr, Vt, Yb);

    // 5. output projection
    gemm128_bt<0><<<dim3(16, 32), 256, 0, stream>>>(Yb, Wpt, out, nullptr, nullptr, nullptr,
                                                    nullptr, 4096, 2048, 2048);
}

// Round 2
// 263.488 us; speedup vs baseline: 1.6140x; 1.6140x over previous
//
#include <hip/hip_runtime.h>
#include <hip/hip_bf16.h>
#include <math.h>

typedef __bf16 bf16;
typedef __bf16 bf16x8 __attribute__((ext_vector_type(8)));
typedef float f32x4 __attribute__((ext_vector_type(4)));
typedef float f32x16 __attribute__((ext_vector_type(16)));
typedef unsigned int u32x2 __attribute__((ext_vector_type(2)));
typedef unsigned int u32x4 __attribute__((ext_vector_type(4)));

#define MFMA16(a, b, c) __builtin_amdgcn_mfma_f32_16x16x32_bf16((a), (b), (c), 0, 0, 0)
#define MFMA32(a, b, c) __builtin_amdgcn_mfma_f32_32x32x16_bf16((a), (b), (c), 0, 0, 0)

static constexpr int Bsz = 2, Tsz = 2048, Csz = 2048, Hn = 16, Dh = 128;
static constexpr float ATTN_SCALE = 0.08838834764831845f; // 1/sqrt(128)

__device__ __forceinline__ void gld16(const void* src, void* dst) {
    __builtin_amdgcn_global_load_lds((__attribute__((address_space(1))) void*)src,
                                     (__attribute__((address_space(3))) void*)dst,
                                     16, 0, 0);
}

__device__ __forceinline__ unsigned cvt_pk_bf16(float lo, float hi) {
    unsigned r;
    asm("v_cvt_pk_bf16_f32 %0, %1, %2" : "=v"(r) : "v"(lo), "v"(hi));
    return r;
}

// Build PV B-operand fragment (keys 16c+8*hl+j, j=0..7 for this lane's q) from
// the lane's own 8 consecutive S^T regs. After the two permlane32 swaps:
//   word0/1 = keys from hl'=0 source, word2/3 = keys from hl'=1 source.
__device__ __forceinline__ bf16x8 make_pfrag(float p0, float p1, float p2, float p3,
                                             float p4, float p5, float p6, float p7) {
    unsigned a0 = cvt_pk_bf16(p0, p1), a1 = cvt_pk_bf16(p2, p3);
    unsigned b0 = cvt_pk_bf16(p4, p5), b1 = cvt_pk_bf16(p6, p7);
    asm volatile("v_permlane32_swap_b32 %0, %1" : "+v"(a0), "+v"(b0));
    asm volatile("v_permlane32_swap_b32 %0, %1" : "+v"(a1), "+v"(b1));
    u32x4 w = {a0, a1, b0, b1};
    return __builtin_bit_cast(bf16x8, w);
}

// ---------------- cast x (f32 -> bf16), 8 elems/thread ----------------
__global__ __launch_bounds__(256) void cast_x_kernel(const float* __restrict__ x,
                                                     bf16* __restrict__ o, int n8) {
    int i = blockIdx.x * 256 + threadIdx.x;
    if (i >= n8) return;
    const float4* x4 = (const float4*)x;
    float4 a = x4[2 * i], b = x4[2 * i + 1];
    bf16x8 v;
    v[0] = (bf16)a.x; v[1] = (bf16)a.y; v[2] = (bf16)a.z; v[3] = (bf16)a.w;
    v[4] = (bf16)b.x; v[5] = (bf16)b.y; v[6] = (bf16)b.z; v[7] = (bf16)b.w;
    ((bf16x8*)o)[i] = v;
}

// ---------------- tiled transpose-cast: out[c][r] = in[r][c] ----------------
template <typename TIN>
__global__ __launch_bounds__(256) void transpose_cast_kernel(const TIN* __restrict__ in,
                                                             bf16* __restrict__ out,
                                                             int R, int Cc) {
    __shared__ float tile[64][65];
    const int tx = threadIdx.x, ty = threadIdx.y;
    in  += (size_t)blockIdx.z * R * Cc;
    out += (size_t)blockIdx.z * R * Cc;
    const int c0 = blockIdx.x * 64, r0 = blockIdx.y * 64;
#pragma unroll
    for (int j = 0; j < 16; ++j) {
        int rr = ty + j * 4;
        tile[rr][tx] = (float)in[(size_t)(r0 + rr) * Cc + c0 + tx];
    }
    __syncthreads();
#pragma unroll
    for (int j = 0; j < 16; ++j) {
        int cc = ty + j * 4;
        out[(size_t)(c0 + cc) * R + r0 + tx] = (bf16)tile[tx][cc];
    }
}

// ---------------- rope cos/sin table ----------------
__global__ __launch_bounds__(256) void cossin_kernel(float2* __restrict__ cs) {
    int idx = blockIdx.x * 256 + threadIdx.x; // 2048*64
    int t = idx >> 6, i = idx & 63;
    float theta = 1.0f / powf(10000.0f, (float)(2 * i) / 128.0f);
    float ang = (float)t * theta;
    cs[idx] = make_float2(cosf(ang), sinf(ang));
}

// ---------------- 128x128 bf16 GEMM, B^T input, BK=64 ----------------
template <int MODE>
__global__ __launch_bounds__(256)
void gemm128_bt(const bf16* __restrict__ A, const bf16* __restrict__ Bt,
                float* __restrict__ Cf,
                bf16* __restrict__ Oq, bf16* __restrict__ Ok, bf16* __restrict__ Ov,
                const float2* __restrict__ cs,
                int M, int N, int K) {
    __shared__ bf16 sA[128 * 64];
    __shared__ bf16 sB[128 * 64];
    const int tid = threadIdx.x;
    const int lane = tid & 63, wv = tid >> 6;
    const int wr = wv >> 1, wc = wv & 1;
    const int lo16 = lane & 15, hi4 = lane >> 4;
    const int row0 = blockIdx.y << 7, col0 = blockIdx.x << 7;

    f32x4 acc[4][4] = {};

    const int nkt = K >> 6;
    for (int kt = 0; kt < nkt; ++kt) {
        const int kbase = kt << 6;
#pragma unroll
        for (int c = 0; c < 4; ++c) {
            const int o16 = (c << 8) + tid;
            const int row = o16 >> 3, u = o16 & 7;
            const int colel = kbase + ((u ^ (row & 7)) << 3); // pre-swizzled source
            gld16(A  + (size_t)(row0 + row) * K + colel,
                  (char*)sA + (((c << 8) + (wv << 6)) << 4));
            gld16(Bt + (size_t)(col0 + row) * K + colel,
                  (char*)sB + (((c << 8) + (wv << 6)) << 4));
        }
        __syncthreads();
#pragma unroll
        for (int ks = 0; ks < 2; ++ks) {
            bf16x8 af[4], bfv[4];
#pragma unroll
            for (int mi = 0; mi < 4; ++mi) {
                const int ar = (wr << 6) + (mi << 4) + lo16;
                af[mi] = *(const bf16x8*)((const char*)sA + ar * 128 +
                          (((ks << 6) + (hi4 << 4)) ^ ((ar & 7) << 4)));
            }
#pragma unroll
            for (int ni = 0; ni < 4; ++ni) {
                const int bc = (wc << 4) + (ni << 5) + lo16;
                bfv[ni] = *(const bf16x8*)((const char*)sB + bc * 128 +
                           (((ks << 6) + (hi4 << 4)) ^ ((bc & 7) << 4)));
            }
#pragma unroll
            for (int mi = 0; mi < 4; ++mi)
#pragma unroll
                for (int ni = 0; ni < 4; ++ni)
                    acc[mi][ni] = MFMA16(af[mi], bfv[ni], acc[mi][ni]);
        }
        __syncthreads();
    }

    if (MODE == 0) {
#pragma unroll
        for (int mi = 0; mi < 4; ++mi)
#pragma unroll
            for (int r = 0; r < 4; ++r) {
                const int gm = row0 + (wr << 6) + (mi << 4) + (hi4 << 2) + r;
                float* crow = Cf + (size_t)gm * N + col0 + (wc << 4) + lo16;
#pragma unroll
                for (int ni = 0; ni < 4; ++ni)
                    crow[ni << 5] = acc[mi][ni][r];
            }
    } else {
        const int seg = col0 >> 11;         // 0=q 1=k 2=v
        const int h = (col0 >> 7) & 15;
        if (seg < 2) {
            bf16* dst0 = (seg == 0) ? Oq : Ok;
            const float qs = (seg == 0) ? ATTN_SCALE : 1.0f; // fold 1/sqrt(D) into Q
#pragma unroll
            for (int mi = 0; mi < 4; ++mi)
#pragma unroll
                for (int r = 0; r < 4; ++r) {
                    const int gm = row0 + (wr << 6) + (mi << 4) + (hi4 << 2) + r;
                    const int b = gm >> 11, t = gm & 2047;
                    bf16* drow = dst0 + ((((size_t)b * Hn + h) * Tsz + t) << 7);
#pragma unroll
                    for (int ni = 0; ni < 2; ++ni) {
                        const int dlo = (wc << 4) + (ni << 5) + lo16; // in [0,64)
                        const float2 csv = cs[t * 64 + dlo];
                        const float vlo = acc[mi][ni][r];
                        const float vhi = acc[mi][ni + 2][r];
                        drow[dlo]      = (bf16)((vlo * csv.x - vhi * csv.y) * qs);
                        drow[dlo + 64] = (bf16)((vhi * csv.x + vlo * csv.y) * qs);
                    }
                }
        } else {
#pragma unroll
            for (int mi = 0; mi < 4; ++mi)
#pragma unroll
                for (int r = 0; r < 4; ++r) {
                    const int gm = row0 + (wr << 6) + (mi << 4) + (hi4 << 2) + r;
                    const int b = gm >> 11, t = gm & 2047;
                    bf16* drow = Ov + ((((size_t)b * Hn + h) * Tsz + t) << 7);
#pragma unroll
                    for (int ni = 0; ni < 4; ++ni)
                        drow[(wc << 4) + (ni << 5) + lo16] = (bf16)acc[mi][ni][r];
                }
        }
    }
}

// ---------------- flash attention: 4 waves x 32 q-rows (QBLK=128), KVBLK=64 ----
// Swapped QK^T (S^T = K*Q) and O^T = V^T * P^T so softmax state is per-lane.
__device__ __forceinline__ void stage_tile(const bf16* __restrict__ Kb,
                                           const bf16* __restrict__ Vtb,
                                           bf16* sKc, bf16* sVc, int k0, int tid) {
#pragma unroll
    for (int c = 0; c < 4; ++c) {
        const int off = (c << 12) + (tid << 4);       // byte offset, 16KB per tensor
        const int row = off >> 8, u = (off >> 4) & 15; // K: 64 rows x 256B
        gld16(Kb + (size_t)(k0 + row) * Dh + ((u ^ (row & 7)) << 3), (char*)sKc + off);
        const int dv = off >> 7, uv = (off >> 4) & 7;  // V^T: 128 rows x 128B
        gld16(Vtb + (size_t)dv * Tsz + k0 + ((uv ^ (dv & 7)) << 3), (char*)sVc + off);
    }
}

__global__ __launch_bounds__(256, 2)
void attn_kernel(const bf16* __restrict__ Q, const bf16* __restrict__ K,
                 const bf16* __restrict__ Vt, bf16* __restrict__ Y) {
    __shared__ bf16 sK[2][64 * 128];
    __shared__ bf16 sV[2][128 * 64];
    const int tid = threadIdx.x, lane = tid & 63, wv = tid >> 6;
    const int lo32 = lane & 31, hl = lane >> 5;

    // paired job mapping: blocks i and i+256 get complementary tiles (t, 15-t)
    const int i = blockIdx.x;
    const int g = i >> 5;
    const int bh = i & 31;
    const int t = (i < 256) ? (15 - g) : (g - 8);
    const int b = bh >> 4, h = bh & 15;

    const int q0 = t << 7;
    const int q0w = q0 + (wv << 5);
    const int qg = q0w + lo32;

    const bf16* Kb  = K  + (size_t)bh * (Tsz * Dh);
    const bf16* Vtb = Vt + (size_t)bh * (Tsz * Dh);
    const bf16* Qp  = Q  + (size_t)bh * (Tsz * Dh) + (size_t)qg * Dh;

    // Q B-operand frags: B[k=16kc+8hl+j][col=q]
    bf16x8 qf[8];
#pragma unroll
    for (int kc = 0; kc < 8; ++kc)
        qf[kc] = *(const bf16x8*)(Qp + (kc << 4) + (hl << 3));

    float m = -1e30f, lsum = 0.f;
    f32x16 o[4] = {};

    const int nt_block = 2 * t + 2;
    const int nt_warp = ((q0w + 31) >> 6) + 1;

    stage_tile(Kb, Vtb, &sK[0][0], &sV[0][0], 0, tid);

    int cur = 0;
    for (int kt = 0; kt < nt_block; ++kt) {
        __syncthreads(); // drains vmcnt -> buf[cur] ready; all waves done with buf[cur^1]
        if (kt + 1 < nt_block)
            stage_tile(Kb, Vtb, &sK[cur ^ 1][0], &sV[cur ^ 1][0], (kt + 1) << 6, tid);
        if (kt < nt_warp) {
            const int k0 = kt << 6;
            const bf16* kbuf = &sK[cur][0];
            const bf16* vbuf = &sV[cur][0];
            f32x16 s0 = {}, s1 = {};
            const int swk = lo32 & 7;
            __builtin_amdgcn_s_setprio(1);
#pragma unroll
            for (int kc = 0; kc < 8; ++kc) {
                bf16x8 kf0 = *(const bf16x8*)((const char*)kbuf + lo32 * 256 +
                              ((((kc << 1) + hl) ^ swk) << 4));
                s0 = MFMA32(kf0, qf[kc], s0);
                bf16x8 kf1 = *(const bf16x8*)((const char*)kbuf + (32 + lo32) * 256 +
                              ((((kc << 1) + hl) ^ swk) << 4));
                s1 = MFMA32(kf1, qf[kc], s1);
            }
            __builtin_amdgcn_s_setprio(0);

            const bool bnd = (k0 + 63 > q0w);
            if (bnd) {
#pragma unroll
                for (int r = 0; r < 16; ++r) {
                    const int kl = (r & 3) + ((r >> 2) << 3) + (hl << 2);
                    if (k0 + kl > qg)      s0[r] = -1e30f;
                    if (k0 + 32 + kl > qg) s1[r] = -1e30f;
                }
            }
            float pm = s0[0];
#pragma unroll
            for (int r = 1; r < 16; ++r) pm = fmaxf(pm, s0[r]);
#pragma unroll
            for (int r = 0; r < 16; ++r) pm = fmaxf(pm, s1[r]);
            pm = fmaxf(pm, __shfl_xor(pm, 32));

            if (__any(pm > m + 8.0f)) { // defer-max (T13)
                const float mn = fmaxf(m, pm);
                const float sc = __expf(m - mn);
                m = mn;
                lsum *= sc;
#pragma unroll
                for (int db = 0; db < 4; ++db)
#pragma unroll
                    for (int r = 0; r < 16; ++r) o[db][r] *= sc;
            }
            float rs = 0.f;
            if (bnd) {
#pragma unroll
                for (int r = 0; r < 16; ++r) {
                    float e0 = (s0[r] > -1e29f) ? __expf(s0[r] - m) : 0.f;
                    float e1 = (s1[r] > -1e29f) ? __expf(s1[r] - m) : 0.f;
                    s0[r] = e0; s1[r] = e1; rs += e0 + e1;
                }
            } else {
#pragma unroll
                for (int r = 0; r < 16; ++r) {
                    float e0 = __expf(s0[r] - m);
                    float e1 = __expf(s1[r] - m);
                    s0[r] = e0; s1[r] = e1; rs += e0 + e1;
                }
            }
            rs += __shfl_xor(rs, 32);
            lsum += rs;

            bf16x8 pb0 = make_pfrag(s0[0], s0[1], s0[2],  s0[3],  s0[4],  s0[5],  s0[6],  s0[7]);
            bf16x8 pb1 = make_pfrag(s0[8], s0[9], s0[10], s0[11], s0[12], s0[13], s0[14], s0[15]);
            bf16x8 pb2 = make_pfrag(s1[0], s1[1], s1[2],  s1[3],  s1[4],  s1[5],  s1[6],  s1[7]);
            bf16x8 pb3 = make_pfrag(s1[8], s1[9], s1[10], s1[11], s1[12], s1[13], s1[14], s1[15]);

            __builtin_amdgcn_s_setprio(1);
#pragma unroll
            for (int db = 0; db < 4; ++db) {
                const int rd = (db << 5) + lo32;
                const char* vrow = (const char*)vbuf + rd * 128;
                const int sw = rd & 7;
                bf16x8 v0 = *(const bf16x8*)(vrow + (((0 + hl) ^ sw) << 4));
                o[db] = MFMA32(v0, pb0, o[db]);
                bf16x8 v1 = *(const bf16x8*)(vrow + (((2 + hl) ^ sw) << 4));
                o[db] = MFMA32(v1, pb1, o[db]);
                bf16x8 v2 = *(const bf16x8*)(vrow + (((4 + hl) ^ sw) << 4));
                o[db] = MFMA32(v2, pb2, o[db]);
                bf16x8 v3 = *(const bf16x8*)(vrow + (((6 + hl) ^ sw) << 4));
                o[db] = MFMA32(v3, pb3, o[db]);
            }
            __builtin_amdgcn_s_setprio(0);
        }
        cur ^= 1;
    }

    const float inv = 1.0f / lsum;
    const size_t rowoff = ((size_t)b * Tsz + qg) * (size_t)Csz + (size_t)h * 128;
#pragma unroll
    for (int db = 0; db < 4; ++db)
#pragma unroll
        for (int gg = 0; gg < 4; ++gg) {
            unsigned w0 = cvt_pk_bf16(o[db][4 * gg + 0] * inv, o[db][4 * gg + 1] * inv);
            unsigned w1 = cvt_pk_bf16(o[db][4 * gg + 2] * inv, o[db][4 * gg + 3] * inv);
            u32x2 w = {w0, w1};
            *(u32x2*)(Y + rowoff + (db << 5) + (gg << 3) + (hl << 2)) = w;
        }
}

extern "C" void kernel_launch(void* const* d_in, const int* in_sizes, int n_in,
                              void* d_out, int out_size, void* d_ws, size_t ws_size,
                              hipStream_t stream) {
    const float* x      = (const float*)d_in[0];
    const float* w_attn = (const float*)d_in[1];
    const float* w_proj = (const float*)d_in[2];
    float* out = (float*)d_out;

    char* ws = (char*)d_ws;
    bf16* Xb  = (bf16*)(ws);                 // 4096x2048           16 MB
    bf16* Wat = (bf16*)(ws + 16777216);      // 6144x2048 (W^T)     24 MB
    bf16* Wpt = (bf16*)(ws + 41943040);      // 2048x2048 (W^T)      8 MB
    bf16* Qr  = (bf16*)(ws + 50331648);      // [B,H,T,D] (scaled)  16 MB
    bf16* Kr  = (bf16*)(ws + 67108864);      // [B,H,T,D]           16 MB
    bf16* Vb  = (bf16*)(ws + 83886080);      // [B,H,T,D]           16 MB
    bf16* Vt  = (bf16*)(ws + 100663296);     // [B,H,D,T]           16 MB
    bf16* Yb  = (bf16*)(ws + 117440512);     // [B,T,C]             16 MB
    float2* cs = (float2*)(ws + 134217728);  // [T,64]               1 MB

    cast_x_kernel<<<4096, 256, 0, stream>>>(x, Xb, (Bsz * Tsz * Csz) / 8);
    transpose_cast_kernel<float><<<dim3(96, 32, 1), dim3(64, 4), 0, stream>>>(w_attn, Wat, 2048, 6144);
    transpose_cast_kernel<float><<<dim3(32, 32, 1), dim3(64, 4), 0, stream>>>(w_proj, Wpt, 2048, 2048);
    cossin_kernel<<<512, 256, 0, stream>>>(cs);

    gemm128_bt<1><<<dim3(48, 32), 256, 0, stream>>>(Xb, Wat, nullptr, Qr, Kr, Vb, cs,
                                                    4096, 6144, 2048);
    transpose_cast_kernel<bf16><<<dim3(2, 32, 32), dim3(64, 4), 0, stream>>>(Vb, Vt, 2048, 128);

    attn_kernel<<<dim3(512), 256, 0, stream>>>(Qr, Kr, Vt, Yb);

    gemm128_bt<0><<<dim3(16, 32), 256, 0, stream>>>(Yb, Wpt, out, nullptr, nullptr, nullptr,
                                                    nullptr, 4096, 2048, 2048);
}